// Round 7
// baseline (53.523 us; speedup 1.0000x reference)
//
#include <hip/hip_runtime.h>

#define IMG 256
#define CROPW 230
#define REMAIN 115
#define NGROUP 16          // channel groups per batch
#define GCH    32          // channels per group (16*32 = 512)
#define TILE_I 16          // output rows per bilinear tile
#define MAXROWS 16         // max input rows per tile
#define NTILE  16          // tiles per image (256 / TILE_I)
#define TPB    3           // tiles per block (2048 blocks * 3 = 6144 tiles)

__device__ __forceinline__ int cut_start(int v) {
    int xy = IMG - v;
    return (v <= REMAIN) ? 0 : ((xy <= REMAIN) ? (IMG - CROPW) : (v - REMAIN));
}

// Async global->LDS DMA: stages 16B/lane; LDS dest is wave-uniform base + lane*16.
__device__ __forceinline__ void load_row16(const float* g, float* l) {
    __builtin_amdgcn_global_load_lds(
        (const __attribute__((address_space(1))) void*)g,
        (__attribute__((address_space(3))) void*)l,
        16, 0, 0);
}

// Grid: 128*16 blocks. Each block: 32 channels of one batch -> partial cam[256].
__global__ __launch_bounds__(256) void cam_partial_kernel(
    const float* __restrict__ fm, float* __restrict__ cam_part)
{
    const int blk = blockIdx.x;
    const int b = blk >> 4;
    const int g = blk & (NGROUP - 1);
    const int tid = threadIdx.x;
    const int lane = tid & 63;
    const int wave = tid >> 6;

    __shared__ float tile[GCH * 256];   // 32 KB
    __shared__ float fw[GCH];

    const float* src = fm + ((size_t)b * 512 + (size_t)g * GCH) * 256;

    const float4* src4 = (const float4*)src;
    float4* tile4 = (float4*)tile;
    #pragma unroll
    for (int k = 0; k < 8; ++k)
        tile4[tid + k * 256] = src4[tid + k * 256];
    __syncthreads();

    for (int c = wave * 8; c < wave * 8 + 8; ++c) {
        const float* row = tile + c * 256;
        float s = row[lane] + row[lane + 64] + row[lane + 128] + row[lane + 192];
        #pragma unroll
        for (int off = 32; off >= 1; off >>= 1)
            s += __shfl_xor(s, off, 64);
        if (lane == 0) fw[c] = s * (1.0f / 256.0f);
    }
    __syncthreads();

    float acc = 0.0f;
    #pragma unroll
    for (int c = 0; c < GCH; ++c) {
        float v = fw[c] * tile[c * 256 + tid];
        acc += (v > 0.0f) ? v : 0.0f;
    }
    cam_part[(size_t)blk * 256 + tid] = acc;   // positive 1/512 scale dropped (argmax-invariant)
}

// Grid: 128 blocks. Sum the 16 partials, argmax (first-occurrence), crop origin.
__global__ __launch_bounds__(256) void argmax_kernel(
    const float* __restrict__ cam_part, int* __restrict__ se_out)
{
    const int b = blockIdx.x;
    const int tid = threadIdx.x;

    __shared__ float s_val[256];
    __shared__ int   s_idx[256];

    float acc = 0.0f;
    #pragma unroll
    for (int g = 0; g < NGROUP; ++g)
        acc += cam_part[((size_t)b * NGROUP + g) * 256 + tid];

    s_val[tid] = acc;
    s_idx[tid] = tid;
    __syncthreads();

    for (int stride = 128; stride >= 1; stride >>= 1) {
        if (tid < stride) {
            float v2 = s_val[tid + stride]; int i2 = s_idx[tid + stride];
            float v1 = s_val[tid];          int i1 = s_idx[tid];
            if (v2 > v1 || (v2 == v1 && i2 < i1)) { s_val[tid] = v2; s_idx[tid] = i2; }
        }
        __syncthreads();
    }

    if (tid == 0) {
        int idx = s_idx[0];
        int fx = idx >> 4, fy = idx & 15;      // H = W = 16
        int ix = 16 * fx,  iy = 16 * fy;       // IMG*fx//H
        se_out[2 * b]     = cut_start(ix);
        se_out[2 * b + 1] = cut_start(iy);
    }
}

// Grid: 2048 blocks, 3 tiles each, double-buffered LDS with async DMA staging:
// issue tile t+1's global_load_lds, compute tile t, drain + barrier (2-phase).
// Per-pixel fp32 math identical to the reference (verified rounds 1-6).
__global__ __launch_bounds__(256) void bilinear_dma_kernel(
    const float* __restrict__ x, const int* __restrict__ se, float* __restrict__ out)
{
    __shared__ float buf[2][MAXROWS * 256];   // 2 x 16 KB

    const int tid  = threadIdx.x;
    const int wave = tid >> 6;
    const int lane = tid & 63;
    const float scale = (float)(229.0 / 255.0);   // (CROP-1)/(IMG-1) in fp32

    const int t0 = blockIdx.x * TPB;
    const int jp  = tid & 127;
    const int ilh = tid >> 7;

    // Prologue: stage tile t0 into buf[0].
    {
        const int bc = t0 >> 4;
        const int ib = (t0 & (NTILE - 1)) * TILE_I;
        const int b  = bc / 3;
        const int x0 = se[2 * b];
        const int r_first = x0 + (int)floorf((float)ib * scale);
        const float* img = x + (size_t)bc * (IMG * IMG);
        #pragma unroll
        for (int k = 0; k < 4; ++k) {
            const int r = wave * 4 + k;
            const int srow = min(r_first + r, IMG - 1);   // clamped rows never read
            load_row16(img + srow * IMG + lane * 4, &buf[0][r * 256]);
        }
    }
    asm volatile("s_waitcnt vmcnt(0)" ::: "memory");
    __syncthreads();

    for (int it = 0; it < TPB; ++it) {
        const int t   = t0 + it;
        const int cur = it & 1;
        const int bc  = t >> 4;
        const int ib  = (t & (NTILE - 1)) * TILE_I;
        const int b   = bc / 3;
        const int x0  = se[2 * b];
        const int y0  = se[2 * b + 1];
        const int r_first = x0 + (int)floorf((float)ib * scale);

        // Issue next tile's DMA into the other buffer; completes under compute.
        if (it + 1 < TPB) {
            const int tn  = t + 1;
            const int bcn = tn >> 4;
            const int ibn = (tn & (NTILE - 1)) * TILE_I;
            const int bn  = bcn / 3;
            const int x0n = se[2 * bn];
            const int rfn = x0n + (int)floorf((float)ibn * scale);
            const float* imgn = x + (size_t)bcn * (IMG * IMG);
            #pragma unroll
            for (int k = 0; k < 4; ++k) {
                const int r = wave * 4 + k;
                const int srow = min(rfn + r, IMG - 1);
                load_row16(imgn + srow * IMG + lane * 4, &buf[cur ^ 1][r * 256]);
            }
        }

        // Compute tile t from buf[cur]: 2 adjacent columns per thread.
        const float* rows = buf[cur];

        const int   ja  = 2 * jp;
        const float sja = (float)ja * scale;
        const int   j0a = (int)floorf(sja);
        const float wja = sja - (float)j0a;
        const int   c0a = y0 + j0a;             // c1a == c0a + 1 always

        const int   jb  = ja + 1;
        const float sjb = (float)jb * scale;
        const int   j0b = (int)floorf(sjb);
        const float wjb = sjb - (float)j0b;
        const int   c1b = y0 + min(j0b + 1, CROPW - 1);
        const bool  bstep = (j0b != j0a);

        float2* outp2 = (float2*)(out + (size_t)bc * (IMG * IMG) + (size_t)ib * IMG) + jp;

        #pragma unroll
        for (int iter = 0; iter < TILE_I / 2; ++iter) {
            const int   il = 2 * iter + ilh;
            const int   i  = ib + il;
            const float si = (float)i * scale;
            const int   i0 = (int)floorf(si);
            const float wi = si - (float)i0;
            const int   i1 = min(i0 + 1, CROPW - 1);
            const int   row0 = (x0 + i0 - r_first) << 8;
            const int   row1 = (x0 + i1 - r_first) << 8;
            const float owi = 1.0f - wi;

            const float t0v = rows[row0 + c0a];
            const float t1v = rows[row0 + c0a + 1];
            const float txv = rows[row0 + c1b];
            const float u0v = rows[row1 + c0a];
            const float u1v = rows[row1 + c0a + 1];
            const float uxv = rows[row1 + c1b];

            // Pixel a (reference blend order).
            const float la = t0v * owi + u0v * wi;
            const float ra = t1v * owi + u1v * wi;
            const float oa = la * (1.0f - wja) + ra * wja;

            // Pixel b.
            const float tb = bstep ? t1v : t0v;
            const float ub = bstep ? u1v : u0v;
            const float lb = tb * owi + ub * wi;
            const float rb = txv * owi + uxv * wi;
            const float ob = lb * (1.0f - wjb) + rb * wjb;

            outp2[il * 128] = make_float2(oa, ob);
        }

        // Drain DMA (and stores), then barrier: next iteration's buffer is ready.
        asm volatile("s_waitcnt vmcnt(0)" ::: "memory");
        __syncthreads();
    }
}

extern "C" void kernel_launch(void* const* d_in, const int* in_sizes, int n_in,
                              void* d_out, int out_size, void* d_ws, size_t ws_size,
                              hipStream_t stream) {
    const float* x  = (const float*)d_in[0];   // (128,3,256,256)
    const float* fm = (const float*)d_in[1];   // (128,512,16,16)
    float* out = (float*)d_out;                // (128,3,256,256)

    int*   se       = (int*)d_ws;                               // 128*2 ints
    float* cam_part = (float*)((char*)d_ws + 1024);             // 128*16*256 floats = 2 MB

    cam_partial_kernel<<<128 * NGROUP, 256, 0, stream>>>(fm, cam_part);
    argmax_kernel<<<128, 256, 0, stream>>>(cam_part, se);

    bilinear_dma_kernel<<<2048, 256, 0, stream>>>(x, se, out);
}

// Round 9
// 51.638 us; speedup vs baseline: 1.0365x; 1.0365x over previous
//
#include <hip/hip_runtime.h>

#define IMG 256
#define CROPW 230
#define REMAIN 115
#define NGROUP 16          // channel groups per batch
#define GCH    32          // channels per group (16*32 = 512)
#define TILE_I 16          // output rows per bilinear tile
#define MAXROWS 16         // max input rows per tile
#define NTILE  16          // tiles per image (256 / TILE_I)

typedef float f32x2 __attribute__((ext_vector_type(2)));

__device__ __forceinline__ int cut_start(int v) {
    int xy = IMG - v;
    return (v <= REMAIN) ? 0 : ((xy <= REMAIN) ? (IMG - CROPW) : (v - REMAIN));
}

// Grid: 128*16 blocks. Each block: 32 channels of one batch -> partial cam[256].
__global__ __launch_bounds__(256) void cam_partial_kernel(
    const float* __restrict__ fm, float* __restrict__ cam_part)
{
    const int blk = blockIdx.x;
    const int b = blk >> 4;
    const int g = blk & (NGROUP - 1);
    const int tid = threadIdx.x;
    const int lane = tid & 63;
    const int wave = tid >> 6;

    __shared__ float tile[GCH * 256];   // 32 KB
    __shared__ float fw[GCH];

    const float* src = fm + ((size_t)b * 512 + (size_t)g * GCH) * 256;

    const float4* src4 = (const float4*)src;
    float4* tile4 = (float4*)tile;
    #pragma unroll
    for (int k = 0; k < 8; ++k)
        tile4[tid + k * 256] = src4[tid + k * 256];
    __syncthreads();

    for (int c = wave * 8; c < wave * 8 + 8; ++c) {
        const float* row = tile + c * 256;
        float s = row[lane] + row[lane + 64] + row[lane + 128] + row[lane + 192];
        #pragma unroll
        for (int off = 32; off >= 1; off >>= 1)
            s += __shfl_xor(s, off, 64);
        if (lane == 0) fw[c] = s * (1.0f / 256.0f);
    }
    __syncthreads();

    float acc = 0.0f;
    #pragma unroll
    for (int c = 0; c < GCH; ++c) {
        float v = fw[c] * tile[c * 256 + tid];
        acc += (v > 0.0f) ? v : 0.0f;
    }
    cam_part[(size_t)blk * 256 + tid] = acc;   // positive 1/512 scale dropped (argmax-invariant)
}

// Grid: 128 blocks. Sum the 16 partials, argmax (first-occurrence), crop origin.
__global__ __launch_bounds__(256) void argmax_kernel(
    const float* __restrict__ cam_part, int* __restrict__ se_out)
{
    const int b = blockIdx.x;
    const int tid = threadIdx.x;

    __shared__ float s_val[256];
    __shared__ int   s_idx[256];

    float acc = 0.0f;
    #pragma unroll
    for (int g = 0; g < NGROUP; ++g)
        acc += cam_part[((size_t)b * NGROUP + g) * 256 + tid];

    s_val[tid] = acc;
    s_idx[tid] = tid;
    __syncthreads();

    for (int stride = 128; stride >= 1; stride >>= 1) {
        if (tid < stride) {
            float v2 = s_val[tid + stride]; int i2 = s_idx[tid + stride];
            float v1 = s_val[tid];          int i1 = s_idx[tid];
            if (v2 > v1 || (v2 == v1 && i2 < i1)) { s_val[tid] = v2; s_idx[tid] = i2; }
        }
        __syncthreads();
    }

    if (tid == 0) {
        int idx = s_idx[0];
        int fx = idx >> 4, fy = idx & 15;      // H = W = 16
        int ix = 16 * fx,  iy = 16 * fy;       // IMG*fx//H
        se_out[2 * b]     = cut_start(ix);
        se_out[2 * b + 1] = cut_start(iy);
    }
}

// Grid: 384 * 16 blocks. Block = one (b,c) image x 16 output rows via 16 KB LDS.
// Each thread computes 2 adjacent output columns; f32x2 NON-TEMPORAL stores
// (out is never re-read — keep it from evicting x out of the 256 MB L3).
// Per-pixel fp32 math identical to the reference (verified rounds 1-7).
__global__ __launch_bounds__(256) void bilinear_tiled_kernel(
    const float* __restrict__ x, const int* __restrict__ se, float* __restrict__ out)
{
    __shared__ float rows[MAXROWS * 256];   // 16 KB

    const int bx = blockIdx.x;
    const int bc = bx >> 4;                 // image index (b*3 + c)
    const int ib = (bx & 15) * TILE_I;      // first output row of this tile
    const int b  = bc / 3;
    const int tid = threadIdx.x;

    const int x0 = se[2 * b];
    const int y0 = se[2 * b + 1];

    const float scale = (float)(229.0 / 255.0);   // (CROP-1)/(IMG-1) in fp32

    // Input row range needed by output rows [ib, ib+TILE_I)
    const int i0_first = (int)floorf((float)ib * scale);
    const int r_first  = x0 + i0_first;

    // Stage a fixed 16 rows (row clamp; clamped rows never read), coalesced float4.
    {
        const float4* src4 = (const float4*)(x + (size_t)bc * (IMG * IMG));
        float4* rows4 = (float4*)rows;
        const int wave = tid >> 6;
        const int lane = tid & 63;
        #pragma unroll
        for (int k = 0; k < 4; ++k) {
            const int row  = 4 * k + wave;
            const int srow = min(r_first + row, IMG - 1);
            rows4[tid + k * 256] = src4[srow * 64 + lane];
        }
    }
    __syncthreads();

    // Thread = columns (2*jp, 2*jp+1) of rows il = 2*iter + ilh.
    const int jp  = tid & 127;
    const int ilh = tid >> 7;

    const int   ja  = 2 * jp;
    const float sja = (float)ja * scale;
    const int   j0a = (int)floorf(sja);
    const float wja = sja - (float)j0a;
    const int   c0a = y0 + j0a;             // c1a == c0a + 1 always (j0a <= 228)

    const int   jb  = ja + 1;
    const float sjb = (float)jb * scale;
    const int   j0b = (int)floorf(sjb);
    const float wjb = sjb - (float)j0b;
    const int   c1b = y0 + min(j0b + 1, CROPW - 1);
    const bool  bstep = (j0b != j0a);       // A_b comes from col c0a+1 if stepped

    f32x2* outp2 = (f32x2*)(out + (size_t)bc * (IMG * IMG) + (size_t)ib * IMG) + jp;

    #pragma unroll
    for (int iter = 0; iter < TILE_I / 2; ++iter) {
        const int   il = 2 * iter + ilh;
        const int   i  = ib + il;
        const float si = (float)i * scale;
        const int   i0 = (int)floorf(si);
        const float wi = si - (float)i0;
        const int   i1 = min(i0 + 1, CROPW - 1);
        const int   row0 = (x0 + i0 - r_first) << 8;
        const int   row1 = (x0 + i1 - r_first) << 8;
        const float owi = 1.0f - wi;

        // 3 reads per row cover both pixels' 2x2 neighborhoods.
        const float t0 = rows[row0 + c0a];
        const float t1 = rows[row0 + c0a + 1];
        const float tx = rows[row0 + c1b];
        const float u0 = rows[row1 + c0a];
        const float u1 = rows[row1 + c0a + 1];
        const float ux = rows[row1 + c1b];

        // Pixel a: A=t0 B=t1 C=u0 D=u1 (reference blend order).
        const float la = t0 * owi + u0 * wi;
        const float ra = t1 * owi + u1 * wi;
        const float oa = la * (1.0f - wja) + ra * wja;

        // Pixel b: A=row[c0b] (select), B=row[c1b].
        const float tb = bstep ? t1 : t0;
        const float ub = bstep ? u1 : u0;
        const float lb = tb * owi + ub * wi;
        const float rb = tx * owi + ux * wi;
        const float ob = lb * (1.0f - wjb) + rb * wjb;

        f32x2 o2; o2.x = oa; o2.y = ob;
        __builtin_nontemporal_store(o2, &outp2[il * 128]);
    }
}

extern "C" void kernel_launch(void* const* d_in, const int* in_sizes, int n_in,
                              void* d_out, int out_size, void* d_ws, size_t ws_size,
                              hipStream_t stream) {
    const float* x  = (const float*)d_in[0];   // (128,3,256,256)
    const float* fm = (const float*)d_in[1];   // (128,512,16,16)
    float* out = (float*)d_out;                // (128,3,256,256)

    int*   se       = (int*)d_ws;                               // 128*2 ints
    float* cam_part = (float*)((char*)d_ws + 1024);             // 128*16*256 floats = 2 MB

    cam_partial_kernel<<<128 * NGROUP, 256, 0, stream>>>(fm, cam_part);
    argmax_kernel<<<128, 256, 0, stream>>>(cam_part, se);

    bilinear_tiled_kernel<<<384 * NTILE, 256, 0, stream>>>(x, se, out);
}